// Round 1
// baseline (404.049 us; speedup 1.0000x reference)
//
#include <hip/hip_runtime.h>
#include <math.h>
#include <limits.h>

#define KTOP 16
#define B1   1024      // pass-1 blocks
#define T1   256       // threads per block

// Comparator implementing jax.lax.top_k ordering: larger value wins,
// ties broken by smaller index.
__device__ __forceinline__ bool key_better(float av, int ai, float bv, int bi) {
    return (av > bv) || (av == bv && ai < bi);
}

__global__ __launch_bounds__(T1) void pass1_topk(const float* __restrict__ P,
                                                 const int*   __restrict__ ipq,
                                                 int n,
                                                 float* __restrict__ cand_v,
                                                 int*   __restrict__ cand_i) {
    const int tid    = threadIdx.x;
    const int gid    = blockIdx.x * T1 + tid;
    const int stride = gridDim.x * T1;

    const int i0 = ipq[0];
    const float pix = P[6 * i0 + 0];
    const float piy = P[6 * i0 + 1];
    const float piz = P[6 * i0 + 2];

    float v[KTOP];
    int   ix[KTOP];
#pragma unroll
    for (int j = 0; j < KTOP; ++j) { v[j] = -INFINITY; ix[j] = INT_MAX; }
    float worst = -INFINITY;

    for (int p = gid; p < n; p += stride) {
        const float2 xy = *(const float2*)(P + 6 * p);
        const float  z  = P[6 * p + 2];
        float d;
        {
#pragma clang fp contract(off)
            const float dx = xy.x - pix;
            const float dy = xy.y - piy;
            const float dz = z    - piz;
            const float s  = (dx * dx + dy * dy) + dz * dz;
            d = sqrtf(s);
        }
        // Per-thread indices ascend, so a value-tie means the incoming
        // candidate loses (larger index). Fast path: single compare.
        if (d > worst) {
            // find worst slot: min value, tie -> larger index
            float wv = v[0]; int wi = ix[0]; int wslot = 0;
#pragma unroll
            for (int j = 1; j < KTOP; ++j)
                if (v[j] < wv || (v[j] == wv && ix[j] > wi)) { wv = v[j]; wi = ix[j]; wslot = j; }
#pragma unroll
            for (int j = 0; j < KTOP; ++j)
                if (wslot == j) { v[j] = d; ix[j] = p; }
            float nw = v[0];
#pragma unroll
            for (int j = 1; j < KTOP; ++j) nw = fminf(nw, v[j]);
            worst = nw;
        }
    }

    // Block pop-max: 16 rounds, emits block top-16 in sorted order.
    __shared__ float s_wv[T1 / 64];
    __shared__ int   s_wi[T1 / 64];
    __shared__ float s_bv;
    __shared__ int   s_bi;

    const int lane   = tid & 63;
    const int waveid = tid >> 6;

    for (int r = 0; r < KTOP; ++r) {
        // local best among my 16 slots
        float bv = v[0]; int bi = ix[0]; int bslot = 0;
#pragma unroll
        for (int j = 1; j < KTOP; ++j)
            if (key_better(v[j], ix[j], bv, bi)) { bv = v[j]; bi = ix[j]; bslot = j; }
        // wave butterfly reduce
        float rv = bv; int ri = bi;
#pragma unroll
        for (int m = 32; m >= 1; m >>= 1) {
            float ov = __shfl_xor(rv, m);
            int   oi = __shfl_xor(ri, m);
            if (key_better(ov, oi, rv, ri)) { rv = ov; ri = oi; }
        }
        if (lane == 0) { s_wv[waveid] = rv; s_wi[waveid] = ri; }
        __syncthreads();
        if (tid == 0) {
            float fv = s_wv[0]; int fi = s_wi[0];
            for (int w = 1; w < T1 / 64; ++w)
                if (key_better(s_wv[w], s_wi[w], fv, fi)) { fv = s_wv[w]; fi = s_wi[w]; }
            s_bv = fv; s_bi = fi;
            cand_v[blockIdx.x * KTOP + r] = fv;
            cand_i[blockIdx.x * KTOP + r] = fi;
        }
        __syncthreads();
        // unique owner (indices are globally unique) invalidates its slot
        if (bv == s_bv && bi == s_bi) {
#pragma unroll
            for (int j = 0; j < KTOP; ++j)
                if (bslot == j) { v[j] = -INFINITY; ix[j] = INT_MAX; }
        }
    }
}

__global__ __launch_bounds__(256) void pass2_final(const float* __restrict__ P,
                                                   const int*   __restrict__ ipq,
                                                   const float* __restrict__ W,
                                                   const float* __restrict__ bvec,
                                                   const float* __restrict__ cand_v,
                                                   const int*   __restrict__ cand_i,
                                                   float* __restrict__ out) {
    const int tid = threadIdx.x;
    const int NC  = B1 * KTOP;

    float v[KTOP];
    int   ix[KTOP];
#pragma unroll
    for (int j = 0; j < KTOP; ++j) { v[j] = -INFINITY; ix[j] = INT_MAX; }
    float worstv = -INFINITY; int worsti = INT_MAX;

    for (int c = tid; c < NC; c += 256) {
        const float d  = cand_v[c];
        const int   id = cand_i[c];
        // candidate stream not index-ordered here -> full key compare
        if (key_better(d, id, worstv, worsti)) {
            float wv = v[0]; int wi = ix[0]; int wslot = 0;
#pragma unroll
            for (int j = 1; j < KTOP; ++j)
                if (v[j] < wv || (v[j] == wv && ix[j] > wi)) { wv = v[j]; wi = ix[j]; wslot = j; }
#pragma unroll
            for (int j = 0; j < KTOP; ++j)
                if (wslot == j) { v[j] = d; ix[j] = id; }
            // recompute worst pair
            wv = v[0]; wi = ix[0];
#pragma unroll
            for (int j = 1; j < KTOP; ++j)
                if (v[j] < wv || (v[j] == wv && ix[j] > wi)) { wv = v[j]; wi = ix[j]; }
            worstv = wv; worsti = wi;
        }
    }

    __shared__ float s_wv[4];
    __shared__ int   s_wi[4];
    __shared__ float s_bv;
    __shared__ int   s_bi;
    __shared__ float s_fv[KTOP];
    __shared__ int   s_fi[KTOP];

    const int lane   = tid & 63;
    const int waveid = tid >> 6;

    for (int r = 0; r < KTOP; ++r) {
        float bv = v[0]; int bi = ix[0]; int bslot = 0;
#pragma unroll
        for (int j = 1; j < KTOP; ++j)
            if (key_better(v[j], ix[j], bv, bi)) { bv = v[j]; bi = ix[j]; bslot = j; }
        float rv = bv; int ri = bi;
#pragma unroll
        for (int m = 32; m >= 1; m >>= 1) {
            float ov = __shfl_xor(rv, m);
            int   oi = __shfl_xor(ri, m);
            if (key_better(ov, oi, rv, ri)) { rv = ov; ri = oi; }
        }
        if (lane == 0) { s_wv[waveid] = rv; s_wi[waveid] = ri; }
        __syncthreads();
        if (tid == 0) {
            float fv = s_wv[0]; int fi = s_wi[0];
            for (int w = 1; w < 4; ++w)
                if (key_better(s_wv[w], s_wi[w], fv, fi)) { fv = s_wv[w]; fi = s_wi[w]; }
            s_bv = fv; s_bi = fi;
            s_fv[r] = fv; s_fi[r] = fi;
        }
        __syncthreads();
        if (bv == s_bv && bi == s_bi) {
#pragma unroll
            for (int j = 0; j < KTOP; ++j)
                if (bslot == j) { v[j] = -INFINITY; ix[j] = INT_MAX; }
        }
    }
    __syncthreads();

    // Epilogue: 16 threads build feat, apply W,b, write [nloc | R].
    if (tid < KTOP) {
        const int   k   = tid;
        const int   idx = s_fi[k];
        const float d   = s_fv[k];
        const int   i0  = ipq[0];
        const float pix = P[6 * i0 + 0], piy = P[6 * i0 + 1], piz = P[6 * i0 + 2];
        const float nx  = P[6 * idx + 0], ny = P[6 * idx + 1], nz = P[6 * idx + 2];
        float dx, dy, dz;
        {
#pragma clang fp contract(off)
            dx = pix - nx; dy = piy - ny; dz = piz - nz;
        }
        const float feat[10] = { pix, piy, piz, nx, ny, nz, dx, dy, dz, d };
        float R[3];
#pragma unroll
        for (int r = 0; r < 3; ++r) {
            float acc = bvec[r];
#pragma unroll
            for (int c = 0; c < 10; ++c) acc += feat[c] * W[r * 10 + c];
            R[r] = acc;
        }
        out[6 * k + 0] = nx;   out[6 * k + 1] = ny;   out[6 * k + 2] = nz;
        out[6 * k + 3] = R[0]; out[6 * k + 4] = R[1]; out[6 * k + 5] = R[2];
    }
}

extern "C" void kernel_launch(void* const* d_in, const int* in_sizes, int n_in,
                              void* d_out, int out_size, void* d_ws, size_t ws_size,
                              hipStream_t stream) {
    const float* P    = (const float*)d_in[0];
    const float* W    = (const float*)d_in[1];
    const float* bvec = (const float*)d_in[2];
    const int*   ipq  = (const int*)d_in[3];
    float*       out  = (float*)d_out;

    const int n = in_sizes[0] / 6;

    float* cand_v = (float*)d_ws;
    int*   cand_i = (int*)((char*)d_ws + (size_t)B1 * KTOP * sizeof(float));

    pass1_topk<<<B1, T1, 0, stream>>>(P, ipq, n, cand_v, cand_i);
    pass2_final<<<1, 256, 0, stream>>>(P, ipq, W, bvec, cand_v, cand_i, out);
}

// Round 2
// 291.132 us; speedup vs baseline: 1.3879x; 1.3879x over previous
//
#include <hip/hip_runtime.h>
#include <math.h>

#define KTOP 16
#define B1   504     // pass-1 blocks (63 per XCD)
#define T1   512     // pass-1 threads per block
#define NC   (B1 * KTOP)   // 8064 candidates
#define T2   512     // pass-2 threads

typedef unsigned long long ull;

// Sortable key: larger distance first, ties -> smaller index first.
// d >= 0 so its float bits are monotone in value.
__device__ __forceinline__ ull pack_key(float d, unsigned idx) {
    return ((ull)__float_as_uint(d) << 32) | (ull)(0xFFFFFFFFu - idx);
}

// Sorted-descending bubble insert, constant indices only (SROA-safe).
__device__ __forceinline__ void insert_key(ull (&k)[KTOP], ull key) {
    ull t = key;
#pragma unroll
    for (int j = 0; j < KTOP; ++j) {
        const ull a = k[j];
        const bool c = (t > a);
        k[j] = c ? t : a;
        t    = c ? a : t;
    }
}

__device__ __forceinline__ float dist3(float x, float y, float z,
                                       float px, float py, float pz) {
#pragma clang fp contract(off)
    const float dx = x - px;
    const float dy = y - py;
    const float dz = z - pz;
    const float s  = (dx * dx + dy * dy) + dz * dz;
    return sqrtf(s);
}

__global__ __launch_bounds__(T1, 1) void pass1_topk(const float* __restrict__ P,
                                                    const int*   __restrict__ ipq,
                                                    int n,
                                                    ull* __restrict__ cand) {
    const int tid    = threadIdx.x;
    const int gid    = blockIdx.x * T1 + tid;
    const int stride = B1 * T1;

    const int i0 = ipq[0];
    const float pix = P[6 * i0 + 0];
    const float piy = P[6 * i0 + 1];
    const float piz = P[6 * i0 + 2];

    ull k[KTOP];
#pragma unroll
    for (int j = 0; j < KTOP; ++j) k[j] = 0ull;

    const float4* __restrict__ P4 = (const float4*)P;
    const int nPairs = n >> 1;

    for (int pp = gid; pp < nPairs; pp += stride) {
        const float4 q0 = P4[3 * pp + 0];
        const float4 q1 = P4[3 * pp + 1];
        const float4 q2 = P4[3 * pp + 2];
        const float dA = dist3(q0.x, q0.y, q0.z, pix, piy, piz);
        const float dB = dist3(q1.z, q1.w, q2.x, pix, piy, piz);
        const ull keyA = pack_key(dA, (unsigned)(2 * pp));
        const ull keyB = pack_key(dB, (unsigned)(2 * pp + 1));
        if (keyA > k[KTOP - 1]) insert_key(k, keyA);
        if (keyB > k[KTOP - 1]) insert_key(k, keyB);
    }
    if ((n & 1) && gid == 0) {
        const int p = n - 1;
        const float d = dist3(P[6 * p], P[6 * p + 1], P[6 * p + 2], pix, piy, piz);
        const ull key = pack_key(d, (unsigned)p);
        if (key > k[KTOP - 1]) insert_key(k, key);
    }

    // Block pop-max: 16 rounds, emit block top-16 sorted descending.
    __shared__ ull s_w[T1 / 64];
    __shared__ ull s_best;
    const int lane = tid & 63;
    const int wid  = tid >> 6;

    for (int r = 0; r < KTOP; ++r) {
        const ull mk = k[0];
        ull rv = mk;
#pragma unroll
        for (int m = 32; m >= 1; m >>= 1) {
            const ull ov = __shfl_xor(rv, m);
            if (ov > rv) rv = ov;
        }
        if (lane == 0) s_w[wid] = rv;
        __syncthreads();
        if (tid == 0) {
            ull b = s_w[0];
            for (int w = 1; w < T1 / 64; ++w) if (s_w[w] > b) b = s_w[w];
            s_best = b;
            cand[blockIdx.x * KTOP + r] = b;
        }
        __syncthreads();
        if (mk == s_best) {   // unique keys -> exactly one owner
#pragma unroll
            for (int j = 0; j < KTOP - 1; ++j) k[j] = k[j + 1];
            k[KTOP - 1] = 0ull;
        }
    }
}

__global__ __launch_bounds__(T2, 1) void pass2_final(const float* __restrict__ P,
                                                     const int*   __restrict__ ipq,
                                                     const float* __restrict__ W,
                                                     const float* __restrict__ bvec,
                                                     const ull*   __restrict__ cand,
                                                     float* __restrict__ out) {
    __shared__ ull keys[NC];          // 64512 B
    __shared__ ull s_w[T2 / 64];
    __shared__ ull s_best;
    __shared__ ull s_final[KTOP];

    const int tid  = threadIdx.x;
    const int lane = tid & 63;
    const int wid  = tid >> 6;

    // Stage candidates to LDS; cache per-thread (max, slot).
    ull mk = 0ull; int ms = -1;
#pragma unroll
    for (int j = 0; j < 16; ++j) {
        const int s = tid + j * T2;
        if (s < NC) {
            const ull v = cand[s];
            keys[s] = v;
            if (v > mk) { mk = v; ms = s; }
        }
    }
    __syncthreads();

    for (int r = 0; r < KTOP; ++r) {
        ull rv = mk;
#pragma unroll
        for (int m = 32; m >= 1; m >>= 1) {
            const ull ov = __shfl_xor(rv, m);
            if (ov > rv) rv = ov;
        }
        if (lane == 0) s_w[wid] = rv;
        __syncthreads();
        if (tid == 0) {
            ull b = s_w[0];
            for (int w = 1; w < T2 / 64; ++w) if (s_w[w] > b) b = s_w[w];
            s_best = b;
            s_final[r] = b;
        }
        __syncthreads();
        const ull best = s_best;
        if (mk == best) {             // unique owner rescans only its slots
            keys[ms] = 0ull;
            mk = 0ull; ms = -1;
#pragma unroll
            for (int j = 0; j < 16; ++j) {
                const int s = tid + j * T2;
                if (s < NC) {
                    const ull v = keys[s];
                    if (v > mk) { mk = v; ms = s; }
                }
            }
        }
    }
    __syncthreads();

    // Epilogue: 16 threads build feat, apply W,b, write [nloc | R].
    if (tid < KTOP) {
        const ull kk = s_final[tid];
        const float d = __uint_as_float((unsigned)(kk >> 32));
        const unsigned idx = 0xFFFFFFFFu - (unsigned)(kk & 0xFFFFFFFFull);
        const int   i0  = ipq[0];
        const float pix = P[6 * i0 + 0], piy = P[6 * i0 + 1], piz = P[6 * i0 + 2];
        const float nx  = P[6 * (size_t)idx + 0];
        const float ny  = P[6 * (size_t)idx + 1];
        const float nz  = P[6 * (size_t)idx + 2];
        float dx, dy, dz;
        {
#pragma clang fp contract(off)
            dx = pix - nx; dy = piy - ny; dz = piz - nz;
        }
        const float feat[10] = { pix, piy, piz, nx, ny, nz, dx, dy, dz, d };
        float R[3];
#pragma unroll
        for (int r = 0; r < 3; ++r) {
            float acc = bvec[r];
#pragma unroll
            for (int c = 0; c < 10; ++c) acc += feat[c] * W[r * 10 + c];
            R[r] = acc;
        }
        out[6 * tid + 0] = nx;   out[6 * tid + 1] = ny;   out[6 * tid + 2] = nz;
        out[6 * tid + 3] = R[0]; out[6 * tid + 4] = R[1]; out[6 * tid + 5] = R[2];
    }
}

extern "C" void kernel_launch(void* const* d_in, const int* in_sizes, int n_in,
                              void* d_out, int out_size, void* d_ws, size_t ws_size,
                              hipStream_t stream) {
    const float* P    = (const float*)d_in[0];
    const float* W    = (const float*)d_in[1];
    const float* bvec = (const float*)d_in[2];
    const int*   ipq  = (const int*)d_in[3];
    float*       out  = (float*)d_out;

    const int n = in_sizes[0] / 6;
    ull* cand = (ull*)d_ws;

    pass1_topk<<<B1, T1, 0, stream>>>(P, ipq, n, cand);
    pass2_final<<<1, T2, 0, stream>>>(P, ipq, W, bvec, cand, out);
}